// Round 1
// baseline (24.581 us; speedup 1.0000x reference)
//
#include <hip/hip_runtime.h>
#include <hip/hip_bf16.h>
#include <math.h>

typedef __attribute__((ext_vector_type(8))) short short8;
typedef __attribute__((ext_vector_type(4))) float f32x4;

#define LOG2E 1.44269504088896340736f

// ---------------- prep: f32 -> bf16 rows, row sq-norms, scale, zero accum ----
// One wave (64 lanes) per row; d = 64 exactly matches wave width.
__global__ __launch_bounds__(256) void kde_prep(
    const float* __restrict__ testX, const float* __restrict__ trainX,
    const float* __restrict__ w,
    __hip_bfloat16* __restrict__ testbf, __hip_bfloat16* __restrict__ trainbf,
    float* __restrict__ sqx, float* __restrict__ sqy, float* __restrict__ nhs,
    float* __restrict__ out_sum, int n_test, int n_train)
{
    int gw = blockIdx.x * 4 + (threadIdx.x >> 6);
    int lane = threadIdx.x & 63;
    if (gw < n_test) {
        int i = gw;
        float x = testX[i * 64 + lane];
        testbf[i * 64 + lane] = __float2bfloat16(x);
        float s = x * x;
        #pragma unroll
        for (int m = 1; m < 64; m <<= 1) s += __shfl_xor(s, m);
        if (lane == 0) { sqx[i] = s; out_sum[i] = 0.0f; }
    } else if (gw < n_test + n_train) {
        int j = gw - n_test;
        float y = trainX[j * 64 + lane];
        trainbf[j * 64 + lane] = __float2bfloat16(y);
        float s = y * y;
        #pragma unroll
        for (int m = 1; m < 64; m <<= 1) s += __shfl_xor(s, m);
        if (lane == 0) {
            sqy[j] = s;
            float ww = w[j];
            nhs[j] = -0.5f * LOG2E * ww * ww;  // p = exp2(dist2 * nhs)
        }
    }
}

// ---------------- main: MFMA cross-product + fused exp-sum epilogue ----------
// Block: 16 test rows x 512 train cols. 4 waves; wave wv covers cols
// [blockIdx.y*512 + wv*128, +128) in 8 steps of 16. K=64 via 2 MFMAs.
// Fragments loaded directly from global (L2-resident bf16 rows):
//   A: lane(l&15) = test row, (l>>4)*8 = k-offset within 32-wide k-slice.
//   B: lane(l&15) = train col, same k packing (consistent A/B packing is
//      sufficient for a full-K dot product).
// C/D layout (HW-verified): col = l&15 (train), row = (l>>4)*4 + reg (test).
__global__ __launch_bounds__(256) void kde_main(
    const __hip_bfloat16* __restrict__ testbf,
    const __hip_bfloat16* __restrict__ trainbf,
    const float* __restrict__ sqx, const float* __restrict__ sqy,
    const float* __restrict__ nhs, float* __restrict__ out_sum)
{
    const int mbase = blockIdx.x * 16;
    const int wv    = threadIdx.x >> 6;
    const int lane  = threadIdx.x & 63;
    const int cg    = lane & 15;   // col-group / A-row selector
    const int kg    = lane >> 4;   // k-chunk selector

    // A fragments: test rows, hoisted out of the col loop.
    const int arow = mbase + cg;
    short8 a0 = *(const short8*)(testbf + arow * 64 +      kg * 8);
    short8 a1 = *(const short8*)(testbf + arow * 64 + 32 + kg * 8);

    // sq-norm of the 4 test rows this lane's accumulator covers.
    float sxr[4];
    #pragma unroll
    for (int r = 0; r < 4; ++r) sxr[r] = sqx[mbase + kg * 4 + r];

    float s[4] = {0.f, 0.f, 0.f, 0.f};
    const int colchunk = blockIdx.y * 512 + wv * 128;

    #pragma unroll
    for (int step = 0; step < 8; ++step) {
        const int bcol = colchunk + step * 16 + cg;
        short8 b0 = *(const short8*)(trainbf + bcol * 64 +      kg * 8);
        short8 b1 = *(const short8*)(trainbf + bcol * 64 + 32 + kg * 8);

        f32x4 acc = {0.f, 0.f, 0.f, 0.f};
        acc = __builtin_amdgcn_mfma_f32_16x16x32_bf16(a0, b0, acc, 0, 0, 0);
        acc = __builtin_amdgcn_mfma_f32_16x16x32_bf16(a1, b1, acc, 0, 0, 0);

        const float sy = sqy[bcol];
        const float nh = nhs[bcol];
        #pragma unroll
        for (int r = 0; r < 4; ++r) {
            float d2 = fmaxf(sxr[r] + sy - 2.0f * acc[r], 0.0f);
            s[r] += exp2f(d2 * nh);
        }
    }

    // Reduce across the 16 col-group lanes (xor bits 0..3 keep kg fixed).
    #pragma unroll
    for (int m = 1; m < 16; m <<= 1) {
        #pragma unroll
        for (int r = 0; r < 4; ++r) s[r] += __shfl_xor(s[r], m);
    }
    if (cg == 0) {
        #pragma unroll
        for (int r = 0; r < 4; ++r)
            atomicAdd(&out_sum[mbase + kg * 4 + r], s[r]);
    }
}

// ---------------- final: log(sum) - Z ---------------------------------------
__global__ __launch_bounds__(256) void kde_final(
    const float* __restrict__ out_sum, float* __restrict__ out, float Z, int n)
{
    int i = blockIdx.x * 256 + threadIdx.x;
    if (i < n) out[i] = logf(out_sum[i]) - Z;
}

extern "C" void kernel_launch(void* const* d_in, const int* in_sizes, int n_in,
                              void* d_out, int out_size, void* d_ws, size_t ws_size,
                              hipStream_t stream) {
    const float* testX  = (const float*)d_in[0];
    const float* trainX = (const float*)d_in[1];
    const float* w      = (const float*)d_in[2];
    float* out = (float*)d_out;

    const int d = 64;
    const int n_test  = in_sizes[0] / d;   // 2048
    const int n_train = in_sizes[1] / d;   // 4096

    char* ws = (char*)d_ws;
    size_t off = 0;
    __hip_bfloat16* testbf  = (__hip_bfloat16*)(ws + off); off += (size_t)n_test  * d * 2;
    __hip_bfloat16* trainbf = (__hip_bfloat16*)(ws + off); off += (size_t)n_train * d * 2;
    float* sqx     = (float*)(ws + off); off += (size_t)n_test  * 4;
    float* sqy     = (float*)(ws + off); off += (size_t)n_train * 4;
    float* nhs     = (float*)(ws + off); off += (size_t)n_train * 4;
    float* out_sum = (float*)(ws + off); off += (size_t)n_test  * 4;
    (void)ws_size; (void)n_in; (void)out_size;

    const float Z = 0.5f * d * logf(2.0f * (float)M_PI) + logf((float)n_train);

    const int rows = n_test + n_train;
    kde_prep<<<(rows + 3) / 4, 256, 0, stream>>>(
        testX, trainX, w, testbf, trainbf, sqx, sqy, nhs, out_sum, n_test, n_train);

    dim3 grid(n_test / 16, n_train / 512);
    kde_main<<<grid, 256, 0, stream>>>(testbf, trainbf, sqx, sqy, nhs, out_sum);

    kde_final<<<(n_test + 255) / 256, 256, 0, stream>>>(out_sum, out, Z, n_test);
}